// Round 16
// baseline (874.211 us; speedup 1.0000x reference)
//
#include <hip/hip_runtime.h>

#define N_PTS 16384
#define BATCH 16
#define NPROP 256
#define NSAMP 16
#define CFEAT 256
#define KIN 259      // 3 + C
#define KPAD 264
#define MBIG 65536   // B*P*NS
#define MSMALL 4096  // B*P
#define NOUT 119
#define NBLK_BIG 512
#define NBLK_SMALL 64

// ---------------- FPS (bit-exact vs numpy) + fused new_pos gather ----------------
// v16 state budget: dd[32] in regs (computed fmin chain - NON-rematerializable,
// allocator keeps it); xyz of pts 0..15 in pinned regs (48); xyz of pts 16..31
// in LDS float4 (1 conflict-free ds_read_b128/pt/iter, no writes, per-thread
// private). 80 named + ~20 temps < the allocator's observed 108-VGPR cap ->
// nothing to spill. R5-R13: 128-value variants spilled ~35; R7/8/14 LDS
// variants paid 3-6 DS ops/pt. This is 1 DS op/pt on half the points.
#define FPS_R16(M) M(0) M(1) M(2) M(3) M(4) M(5) M(6) M(7) \
  M(8) M(9) M(10) M(11) M(12) M(13) M(14) M(15)

#define FPS_PIN8(a,b,c,d,e,f,g,h) \
  asm volatile("" : "+v"(a), "+v"(b), "+v"(c), "+v"(d), \
                    "+v"(e), "+v"(f), "+v"(g), "+v"(h));

__global__ __attribute__((amdgpu_flat_work_group_size(512,512), amdgpu_waves_per_eu(2,2)))
void fps_kernel(const float* __restrict__ sp, const float* __restrict__ pos,
                int* __restrict__ idx_p, float* __restrict__ npos) {
#pragma clang fp contract(off)
  __shared__ float4 hxyz[8192];                // pts 8192..16383, 128 KB
  __shared__ unsigned long long part[2][8];
  __shared__ int sidx[NPROP];
  const int b = blockIdx.x;
  const int t = threadIdx.x;
  const int w = t >> 6;
  const int lane = t & 63;
  const float* base = sp + (size_t)b * N_PTS * 3;
  const float4* h_lo = hxyz;           // J=16..23: off t*16 + (J-16)*8192 <= 65520
  const float4* h_hi = hxyz + 4096;    // J=24..31

#define FPS_DECL(J) float px##J, py##J, pz##J;
  FPS_R16(FPS_DECL)
#undef FPS_DECL
  float dd0,dd1,dd2,dd3,dd4,dd5,dd6,dd7,dd8,dd9,dd10,dd11,dd12,dd13,dd14,dd15,
        dd16,dd17,dd18,dd19,dd20,dd21,dd22,dd23,dd24,dd25,dd26,dd27,dd28,dd29,dd30,dd31;

#define FPS_INIT(J) { const int i = t + J*512; \
    px##J = base[i*3+0]; py##J = base[i*3+1]; pz##J = base[i*3+2]; }
  FPS_R16(FPS_INIT)
#undef FPS_INIT
#define FPS_INITH(J) { const int i = t + J*512; \
    hxyz[t + (J-16)*512] = make_float4(base[i*3+0], base[i*3+1], base[i*3+2], 0.f); }
  FPS_INITH(16) FPS_INITH(17) FPS_INITH(18) FPS_INITH(19)
  FPS_INITH(20) FPS_INITH(21) FPS_INITH(22) FPS_INITH(23)
  FPS_INITH(24) FPS_INITH(25) FPS_INITH(26) FPS_INITH(27)
  FPS_INITH(28) FPS_INITH(29) FPS_INITH(30) FPS_INITH(31)
#undef FPS_INITH
  dd0=dd1=dd2=dd3=dd4=dd5=dd6=dd7=dd8=dd9=dd10=dd11=dd12=dd13=dd14=dd15=1e10f;
  dd16=dd17=dd18=dd19=dd20=dd21=dd22=dd23=dd24=dd25=dd26=dd27=dd28=dd29=dd30=dd31=1e10f;

  FPS_PIN8(px0,px1,px2,px3,px4,px5,px6,px7)
  FPS_PIN8(px8,px9,px10,px11,px12,px13,px14,px15)
  FPS_PIN8(py0,py1,py2,py3,py4,py5,py6,py7)
  FPS_PIN8(py8,py9,py10,py11,py12,py13,py14,py15)
  FPS_PIN8(pz0,pz1,pz2,pz3,pz4,pz5,pz6,pz7)
  FPS_PIN8(pz8,pz9,pz10,pz11,pz12,pz13,pz14,pz15)

  if (t == 0) { idx_p[b*NPROP] = 0; sidx[0] = 0; }
  float fx = base[0], fy = base[1], fz = base[2];
  for (int it = 1; it < NPROP; ++it) {
    float mv = -1.0f; int mi = 0;
#define FPS_STEP(J) { \
    float dx = px##J - fx, dy = py##J - fy, dz = pz##J - fz; \
    float d = (dx*dx + dy*dy) + dz*dz; \
    float nd = fminf(dd##J, d); \
    dd##J = nd; \
    if (nd > mv) { mv = nd; mi = t + J*512; } }
    FPS_R16(FPS_STEP)
#undef FPS_STEP
#define FPS_STEPH(J) { \
    const float4 v = (J < 24) ? h_lo[t + (J-16)*512] : h_hi[t + (J-24)*512]; \
    float dx = v.x - fx, dy = v.y - fy, dz = v.z - fz; \
    float d = (dx*dx + dy*dy) + dz*dz; \
    float nd = fminf(dd##J, d); \
    dd##J = nd; \
    if (nd > mv) { mv = nd; mi = t + J*512; } }
    FPS_STEPH(16) FPS_STEPH(17) FPS_STEPH(18) FPS_STEPH(19)
    FPS_STEPH(20) FPS_STEPH(21) FPS_STEPH(22) FPS_STEPH(23)
    FPS_STEPH(24) FPS_STEPH(25) FPS_STEPH(26) FPS_STEPH(27)
    FPS_STEPH(28) FPS_STEPH(29) FPS_STEPH(30) FPS_STEPH(31)
#undef FPS_STEPH
    // pack: larger value wins; tie -> smaller index (numpy argmax semantics)
    unsigned long long key =
      ((unsigned long long)__float_as_uint(mv) << 32) |
      (unsigned long long)(unsigned)(0x7FFFFFFF - mi);
#pragma unroll
    for (int o = 32; o > 0; o >>= 1) {
      unsigned long long ok = __shfl_xor(key, o, 64);
      if (ok > key) key = ok;
    }
    const int buf = it & 1;
    if (lane == 0) part[buf][w] = key;
    __syncthreads();
    unsigned long long k2 = part[buf][0];
#pragma unroll
    for (int q = 1; q < 8; ++q) {
      unsigned long long ok = part[buf][q];
      if (ok > k2) k2 = ok;
    }
    const int far = 0x7FFFFFFF - (int)(unsigned)(k2 & 0xFFFFFFFFull);
    if (t == 0) { idx_p[b*NPROP + it] = far; sidx[it] = far; }
    const float* fp = base + (size_t)far*3;
    fx = fp[0]; fy = fp[1]; fz = fp[2];
  }
  // fused new_pos gather (from pos, not seed_pos)
  __syncthreads();
  if (t < NPROP) {
    const int ii = sidx[t];
    const float* pp = pos + ((size_t)b*N_PTS + ii)*3;
    float* np = npos + (size_t)(b*NPROP + t)*3;
    np[0] = pp[0]; np[1] = pp[1]; np[2] = pp[2];
  }
}

// ---------------- ball query ----------------
__global__ __launch_bounds__(256)
void ballq_kernel(const float* __restrict__ pos, const float* __restrict__ npos,
                  int* __restrict__ idxg) {
#pragma clang fp contract(off)
  __shared__ int res[4][NSAMP];
  const int tid = threadIdx.x;
  const int w = tid >> 6, lane = tid & 63;
  const int cid = blockIdx.x*4 + w;     // 0..4095
  const int b = cid >> 8;
  const float R2 = (float)(0.3*0.3);
  if (lane == 0) res[w][0] = 0;
  const float cx = npos[cid*3+0], cy = npos[cid*3+1], cz = npos[cid*3+2];
  const float* pb = pos + (size_t)b*N_PTS*3;
  int cnt = 0;
  const unsigned long long lmask = (1ull << lane) - 1ull;
#pragma unroll 4
  for (int ch = 0; ch < N_PTS/64; ++ch) {
    int i = ch*64 + lane;
    float dx = pb[i*3+0]-cx, dy = pb[i*3+1]-cy, dz = pb[i*3+2]-cz;
    float d2 = (dx*dx + dy*dy) + dz*dz;
    bool pred = d2 <= R2;
    unsigned long long bal = __ballot(pred);
    if (pred) {
      int slot = cnt + (int)__popcll(bal & lmask);
      if (slot < NSAMP) res[w][slot] = i;
    }
    cnt += (int)__popcll(bal);
  }
  __syncthreads();
  if (lane < NSAMP) {
    int v = res[w][lane];
    if (lane >= cnt) v = res[w][0];
    idxg[cid*NSAMP + lane] = v;
  }
}

// ---------------- weight padding ----------------
__global__ __launch_bounds__(256)
void prep_w(const float* __restrict__ w0, const float* __restrict__ c2w,
            const float* __restrict__ c2b, const float* __restrict__ c3w,
            const float* __restrict__ c3b,
            float* __restrict__ Wp0, float* __restrict__ Wp2, float* __restrict__ B2p,
            float* __restrict__ Wp3, float* __restrict__ B3p) {
  int g = blockIdx.x*256 + threadIdx.x;
  const int S0 = KPAD*128, S1 = S0 + 16384, S2 = S1 + 128, S3 = S2 + 16384, S4 = S3 + 128;
  if (g < S0) {
    int k = g >> 7, n = g & 127;
    Wp0[g] = (k < KIN) ? w0[k*128 + n] : 0.f;
  } else if (g < S1) {
    int g2 = g - S0; int k = g2 >> 7, n = g2 & 127;
    Wp2[g2] = (n < 123) ? c2w[k*123 + n] : 0.f;
  } else if (g < S2) {
    int n = g - S1;
    B2p[n] = (n < 123) ? c2b[n] : 0.f;
  } else if (g < S3) {
    int g2 = g - S2; int k = g2 >> 7, n = g2 & 127;
    Wp3[g2] = (k < 123 && n < NOUT) ? c3w[k*NOUT + n] : 0.f;
  } else if (g < S4) {
    int n = g - S3;
    B3p[n] = (n < NOUT) ? c3b[n] : 0.f;
  }
}

// ---------------- layer-0 GEMM with fused gather + fused partial stats ----------------
__global__ __launch_bounds__(256)
void gemm_l0(const float* __restrict__ pos, const float* __restrict__ npos,
             const float* __restrict__ feat, const int* __restrict__ idxg,
             const float* __restrict__ Wp, const float* __restrict__ bias,
             float* __restrict__ H, float* __restrict__ Sp, float* __restrict__ Qp) {
  __shared__ float As[8][128];
  __shared__ float Ws[8][128];
  __shared__ float pd[3][128];
  __shared__ int ids[128];
  const int tid = threadIdx.x;
  const int m0 = blockIdx.x * 128;
  const int b = m0 >> 12;
  const float* fb = feat + (size_t)b * CFEAT * N_PTS;
  if (tid < 128) {
    int m = m0 + tid;
    int ii = idxg[m];
    ids[tid] = ii;
    int q = m >> 4;
    const float* pp = pos + ((size_t)b*N_PTS + ii)*3;
    const float* cc = npos + (size_t)q*3;
    pd[0][tid] = pp[0] - cc[0];
    pd[1][tid] = pp[1] - cc[1];
    pd[2][tid] = pp[2] - cc[2];
  }
  __syncthreads();
  const int kr = tid >> 5;
  const int cm = (tid & 31) * 4;
  int ii_r[4];
#pragma unroll
  for (int x = 0; x < 4; ++x) ii_r[x] = ids[cm+x];
  float acc[8][8];
#pragma unroll
  for (int i = 0; i < 8; ++i)
#pragma unroll
    for (int j = 0; j < 8; ++j) acc[i][j] = 0.f;
  const int tm = tid & 15, tn = tid >> 4;
  for (int k0 = 0; k0 < KPAD; k0 += 8) {
    const int k = k0 + kr;
    float4 a0;
    if (k < 3) {
      a0.x = pd[k][cm+0]; a0.y = pd[k][cm+1]; a0.z = pd[k][cm+2]; a0.w = pd[k][cm+3];
    } else if (k < KIN) {
      const float* fr = fb + (size_t)(k-3)*N_PTS;
      a0.x = fr[ii_r[0]]; a0.y = fr[ii_r[1]]; a0.z = fr[ii_r[2]]; a0.w = fr[ii_r[3]];
    } else {
      a0 = make_float4(0.f,0.f,0.f,0.f);
    }
    float4 wv = *(const float4*)(Wp + (size_t)k*128 + cm);
    __syncthreads();
    *(float4*)&As[kr][cm] = a0;
    *(float4*)&Ws[kr][cm] = wv;
    __syncthreads();
#pragma unroll
    for (int kk = 0; kk < 8; ++kk) {
      float a[8], bb[8];
      *(float4*)(a)   = *(const float4*)&As[kk][tm*4];
      *(float4*)(a+4) = *(const float4*)&As[kk][tm*4 + 64];
      *(float4*)(bb)   = *(const float4*)&Ws[kk][tn*8];
      *(float4*)(bb+4) = *(const float4*)&Ws[kk][tn*8+4];
#pragma unroll
      for (int i = 0; i < 8; ++i)
#pragma unroll
        for (int j = 0; j < 8; ++j)
          acc[i][j] = fmaf(a[i], bb[j], acc[i][j]);
    }
  }
#pragma unroll
  for (int j = 0; j < 8; ++j) {
    const int n = tn*8 + j;
    const float bv = bias[n];
    float* cr = H + (size_t)n*MBIG + m0 + tm*4;
    float4 o0, o1;
    o0.x = acc[0][j]+bv; o0.y = acc[1][j]+bv; o0.z = acc[2][j]+bv; o0.w = acc[3][j]+bv;
    o1.x = acc[4][j]+bv; o1.y = acc[5][j]+bv; o1.z = acc[6][j]+bv; o1.w = acc[7][j]+bv;
    *(float4*)(cr)      = o0;
    *(float4*)(cr + 64) = o1;
    float s = o0.x+o0.y+o0.z+o0.w + o1.x+o1.y+o1.z+o1.w;
    float q = o0.x*o0.x+o0.y*o0.y+o0.z*o0.z+o0.w*o0.w
            + o1.x*o1.x+o1.y*o1.y+o1.z*o1.z+o1.w*o1.w;
#pragma unroll
    for (int o = 1; o < 16; o <<= 1) {
      s += __shfl_xor(s, o, 64);
      q += __shfl_xor(q, o, 64);
    }
    if (tm == 0) {
      Sp[(size_t)n*NBLK_BIG + blockIdx.x] = s;
      Qp[(size_t)n*NBLK_BIG + blockIdx.x] = q;
    }
  }
}

// ---------------- big GEMM (M=MBIG, K=N=128): W LDS-resident, dbuf A, 1 barrier/step ----------------
__global__ __launch_bounds__(256)
void gemm_big(const float* __restrict__ A, const float* __restrict__ W,
              const float* __restrict__ bias, const float* __restrict__ sc,
              const float* __restrict__ sh, float* __restrict__ C,
              float* __restrict__ Sp, float* __restrict__ Qp) {
  __shared__ float Ws[128][128];   // 64 KB, whole W resident
  __shared__ float As[2][8][128];  // 8 KB double buffer
  const int tid = threadIdx.x;
  const int m0 = blockIdx.x * 128;
  const int kr = tid >> 5;
  const int cw = (tid & 31) * 4;
  const int tm = tid & 15, tn = tid >> 4;
#pragma unroll
  for (int rr = 0; rr < 16; ++rr) {
    const int k = rr*8 + kr;
    *(float4*)&Ws[k][cw] = *(const float4*)(W + (size_t)k*128 + cw);
  }
  {
    float4 a0 = *(const float4*)(A + (size_t)kr*MBIG + m0 + cw);
    const float s_ = sc[kr], h_ = sh[kr];
    a0.x = fmaxf(fmaf(a0.x, s_, h_), 0.f);
    a0.y = fmaxf(fmaf(a0.y, s_, h_), 0.f);
    a0.z = fmaxf(fmaf(a0.z, s_, h_), 0.f);
    a0.w = fmaxf(fmaf(a0.w, s_, h_), 0.f);
    *(float4*)&As[0][kr][cw] = a0;
  }
  __syncthreads();
  float acc[8][8];
#pragma unroll
  for (int i = 0; i < 8; ++i)
#pragma unroll
    for (int j = 0; j < 8; ++j) acc[i][j] = 0.f;
  for (int step = 0; step < 16; ++step) {
    const int cur = step & 1;
    float4 a1;
    if (step < 15) {
      const int k = (step+1)*8 + kr;
      a1 = *(const float4*)(A + (size_t)k*MBIG + m0 + cw);
      const float s_ = sc[k], h_ = sh[k];
      a1.x = fmaxf(fmaf(a1.x, s_, h_), 0.f);
      a1.y = fmaxf(fmaf(a1.y, s_, h_), 0.f);
      a1.z = fmaxf(fmaf(a1.z, s_, h_), 0.f);
      a1.w = fmaxf(fmaf(a1.w, s_, h_), 0.f);
    }
#pragma unroll
    for (int kk = 0; kk < 8; ++kk) {
      float a[8], bb[8];
      *(float4*)(a)   = *(const float4*)&As[cur][kk][tm*4];
      *(float4*)(a+4) = *(const float4*)&As[cur][kk][tm*4 + 64];
      *(float4*)(bb)   = *(const float4*)&Ws[step*8+kk][tn*8];
      *(float4*)(bb+4) = *(const float4*)&Ws[step*8+kk][tn*8+4];
#pragma unroll
      for (int i = 0; i < 8; ++i)
#pragma unroll
        for (int j = 0; j < 8; ++j)
          acc[i][j] = fmaf(a[i], bb[j], acc[i][j]);
    }
    if (step < 15) *(float4*)&As[cur^1][kr][cw] = a1;
    __syncthreads();
  }
#pragma unroll
  for (int j = 0; j < 8; ++j) {
    const int n = tn*8 + j;
    const float bv = bias[n];
    float* cr = C + (size_t)n*MBIG + m0 + tm*4;
    float4 o0, o1;
    o0.x = acc[0][j]+bv; o0.y = acc[1][j]+bv; o0.z = acc[2][j]+bv; o0.w = acc[3][j]+bv;
    o1.x = acc[4][j]+bv; o1.y = acc[5][j]+bv; o1.z = acc[6][j]+bv; o1.w = acc[7][j]+bv;
    *(float4*)(cr)      = o0;
    *(float4*)(cr + 64) = o1;
    float s = o0.x+o0.y+o0.z+o0.w + o1.x+o1.y+o1.z+o1.w;
    float q = o0.x*o0.x+o0.y*o0.y+o0.z*o0.z+o0.w*o0.w
            + o1.x*o1.x+o1.y*o1.y+o1.z*o1.z+o1.w*o1.w;
#pragma unroll
    for (int o = 1; o < 16; o <<= 1) {
      s += __shfl_xor(s, o, 64);
      q += __shfl_xor(q, o, 64);
    }
    if (tm == 0) {
      Sp[(size_t)n*NBLK_BIG + blockIdx.x] = s;
      Qp[(size_t)n*NBLK_BIG + blockIdx.x] = q;
    }
  }
}

// ---------------- small GEMM, TM=64 tiles, optional fused partial stats ----------------
template<int TM, int MODE, int DOPART>
__global__ __launch_bounds__(256)
void gemm_k(const float* __restrict__ A, const float* __restrict__ W,
            const float* __restrict__ bias, const float* __restrict__ sc,
            const float* __restrict__ sh, float* __restrict__ C,
            float* __restrict__ Sp, float* __restrict__ Qp,
            int M, int K, int useT) {
  __shared__ float As[8][TM];
  __shared__ float Ws[8][128];
  const int tid = threadIdx.x;
  const int m0 = blockIdx.x * TM;
  const int kr = tid >> 5;
  const int cw = (tid & 31) * 4;
  const int tm = tid & 15, tn = tid >> 4;
  constexpr int MR = TM / 16;
  constexpr int NBLK = (TM == 128) ? NBLK_BIG : NBLK_SMALL;
  float acc[MR][8];
#pragma unroll
  for (int i = 0; i < MR; ++i)
#pragma unroll
    for (int j = 0; j < 8; ++j) acc[i][j] = 0.f;
  for (int k0 = 0; k0 < K; k0 += 8) {
    const float* ar = A + (size_t)(k0+kr)*M + m0;
    float4 wv = *(const float4*)(W + (size_t)(k0+kr)*128 + cw);
    const float s_ = useT ? sc[k0+kr] : 1.f;
    const float h_ = useT ? sh[k0+kr] : 0.f;
    const int c2 = (tid & 31) * 2;
    float2 a0 = *(const float2*)(ar + c2);
    if (useT) {
      a0.x = fmaxf(fmaf(a0.x, s_, h_), 0.f);
      a0.y = fmaxf(fmaf(a0.y, s_, h_), 0.f);
    }
    __syncthreads();
    *(float2*)&As[kr][c2] = a0;
    *(float4*)&Ws[kr][cw] = wv;
    __syncthreads();
#pragma unroll
    for (int kk = 0; kk < 8; ++kk) {
      float a[MR], bb[8];
      *(float4*)(a) = *(const float4*)&As[kk][tm*4];
      *(float4*)(bb)   = *(const float4*)&Ws[kk][tn*8];
      *(float4*)(bb+4) = *(const float4*)&Ws[kk][tn*8+4];
#pragma unroll
      for (int i = 0; i < MR; ++i)
#pragma unroll
        for (int j = 0; j < 8; ++j)
          acc[i][j] = fmaf(a[i], bb[j], acc[i][j]);
    }
  }
  if (MODE == 0) {
#pragma unroll
    for (int j = 0; j < 8; ++j) {
      const int n = tn*8 + j;
      const float bv = bias[n];
      float* cr = C + (size_t)n*M + m0 + tm*4;
      float4 o0;
      o0.x = acc[0][j]+bv; o0.y = acc[1][j]+bv; o0.z = acc[2][j]+bv; o0.w = acc[3][j]+bv;
      *(float4*)(cr) = o0;
      if constexpr (DOPART) {
        float s = o0.x+o0.y+o0.z+o0.w;
        float q = o0.x*o0.x+o0.y*o0.y+o0.z*o0.z+o0.w*o0.w;
#pragma unroll
        for (int o = 1; o < 16; o <<= 1) {
          s += __shfl_xor(s, o, 64);
          q += __shfl_xor(q, o, 64);
        }
        if (tm == 0) {
          Sp[(size_t)n*NBLK + blockIdx.x] = s;
          Qp[(size_t)n*NBLK + blockIdx.x] = q;
        }
      }
    }
  } else {
    const int bb_ = m0 >> 8;
    const int pcol = (m0 & 255) + tm*4;
#pragma unroll
    for (int j = 0; j < 8; ++j) {
      const int n = tn*8 + j;
      if (n < NOUT) {
        const float bv = bias[n];
        float* cr = C + ((size_t)bb_*NOUT + n)*256 + pcol;
        float4 o0;
        o0.x = acc[0][j]+bv; o0.y = acc[1][j]+bv; o0.z = acc[2][j]+bv; o0.w = acc[3][j]+bv;
        *(float4*)(cr) = o0;
      }
    }
  }
}

// ---------------- stats finish: reduce per-block partials -> (scale, shift) ----------------
__global__ __launch_bounds__(256)
void stats_finish(const float* __restrict__ Sp, const float* __restrict__ Qp,
                  int nblk, int M, int nc,
                  const float* __restrict__ g, const float* __restrict__ be,
                  float* __restrict__ sc, float* __restrict__ sh) {
  const int c = blockIdx.x;
  const int tid = threadIdx.x;
  if (c >= nc) { if (tid == 0) { sc[c] = 0.f; sh[c] = 0.f; } return; }
  float s = 0.f, q = 0.f;
  for (int i = tid; i < nblk; i += 256) {
    s += Sp[(size_t)c*nblk + i];
    q += Qp[(size_t)c*nblk + i];
  }
#pragma unroll
  for (int o = 32; o > 0; o >>= 1) {
    s += __shfl_xor(s, o, 64);
    q += __shfl_xor(q, o, 64);
  }
  __shared__ float ws_[4], wq_[4];
  const int w = tid >> 6, lane = tid & 63;
  if (lane == 0) { ws_[w] = s; wq_[w] = q; }
  __syncthreads();
  if (tid == 0) {
    float S = ws_[0]+ws_[1]+ws_[2]+ws_[3];
    float Q = wq_[0]+wq_[1]+wq_[2]+wq_[3];
    float mean = S / (float)M;
    float var  = Q / (float)M - mean*mean;
    float inv  = rsqrtf(var + 1e-5f);
    float gg = g[c];
    sc[c] = inv * gg;
    sh[c] = be[c] - mean * inv * gg;
  }
}

// ---------------- BN+ReLU then max over NSAMP ----------------
__global__ __launch_bounds__(256)
void pool_kernel(const float* __restrict__ H2, const float* __restrict__ sc,
                 const float* __restrict__ sh, float* __restrict__ X3) {
  int gidx = blockIdx.x*256 + threadIdx.x;
  int c = gidx >> 12;
  int q = gidx & 4095;
  const float* src = H2 + (size_t)c*MBIG + (size_t)q*NSAMP;
  float s_ = sc[c], h_ = sh[c];
  float m = 0.f;
#pragma unroll
  for (int k = 0; k < NSAMP; k += 4) {
    float4 v = *(const float4*)(src + k);
    m = fmaxf(m, fmaf(v.x, s_, h_));
    m = fmaxf(m, fmaf(v.y, s_, h_));
    m = fmaxf(m, fmaf(v.z, s_, h_));
    m = fmaxf(m, fmaf(v.w, s_, h_));
  }
  X3[(size_t)c*MSMALL + q] = m;
}

extern "C" void kernel_launch(void* const* d_in, const int* in_sizes, int n_in,
                              void* d_out, int out_size, void* d_ws, size_t ws_size,
                              hipStream_t stream) {
  const float* pos  = (const float*)d_in[0];
  const float* feat = (const float*)d_in[1];
  const float* spos = (const float*)d_in[2];
  const float* w0  = (const float*)d_in[3];
  const float* b0  = (const float*)d_in[4];
  const float* g0  = (const float*)d_in[5];
  const float* be0 = (const float*)d_in[6];
  const float* w1  = (const float*)d_in[7];
  const float* b1  = (const float*)d_in[8];
  const float* g1  = (const float*)d_in[9];
  const float* be1 = (const float*)d_in[10];
  const float* w2  = (const float*)d_in[11];
  const float* b2  = (const float*)d_in[12];
  const float* g2  = (const float*)d_in[13];
  const float* be2 = (const float*)d_in[14];
  const float* c1w = (const float*)d_in[15];
  const float* c1b = (const float*)d_in[16];
  const float* bg1 = (const float*)d_in[17];
  const float* bb1 = (const float*)d_in[18];
  const float* c2w = (const float*)d_in[19];
  const float* c2b = (const float*)d_in[20];
  const float* bg2 = (const float*)d_in[21];
  const float* bb2 = (const float*)d_in[22];
  const float* c3w = (const float*)d_in[23];
  const float* c3b = (const float*)d_in[24];
  float* out = (float*)d_out;

  float* fws = (float*)d_ws;
  size_t off = 0;
  auto alloc = [&](size_t n) { float* p = fws + off; off += n; return p; };
  float* H0  = alloc((size_t)128*MBIG);
  float* H1  = alloc((size_t)128*MBIG);
  float* X3  = alloc((size_t)128*MSMALL);
  float* H3  = alloc((size_t)128*MSMALL);
  float* H4  = alloc((size_t)128*MSMALL);
  float* Wp0 = alloc(KPAD*128);
  float* Wp2 = alloc(16384);
  float* B2p = alloc(128);
  float* Wp3 = alloc(16384);
  float* B3p = alloc(128);
  float* sc0 = alloc(128); float* sh0 = alloc(128);
  float* sc1 = alloc(128); float* sh1 = alloc(128);
  float* sc2 = alloc(128); float* sh2 = alloc(128);
  float* sc3 = alloc(128); float* sh3 = alloc(128);
  float* sc4 = alloc(128); float* sh4 = alloc(128);
  float* Sp  = alloc((size_t)128*NBLK_BIG);
  float* Qp  = alloc((size_t)128*NBLK_BIG);
  float* npos = alloc((size_t)BATCH*NPROP*3);
  int* idx_p = (int*)alloc(BATCH*NPROP);
  int* idxg  = (int*)alloc(MBIG);
  float* H2 = H0;

  fps_kernel<<<BATCH, 512, 0, stream>>>(spos, pos, idx_p, npos);
  ballq_kernel<<<BATCH*NPROP/4, 256, 0, stream>>>(pos, npos, idxg);
  prep_w<<<261, 256, 0, stream>>>(w0, c2w, c2b, c3w, c3b, Wp0, Wp2, B2p, Wp3, B3p);

  gemm_l0<<<MBIG/128, 256, 0, stream>>>(pos, npos, feat, idxg, Wp0, b0, H0, Sp, Qp);
  stats_finish<<<128, 256, 0, stream>>>(Sp, Qp, NBLK_BIG, MBIG, 128, g0, be0, sc0, sh0);
  gemm_big<<<MBIG/128, 256, 0, stream>>>(H0, w1, b1, sc0, sh0, H1, Sp, Qp);
  stats_finish<<<128, 256, 0, stream>>>(Sp, Qp, NBLK_BIG, MBIG, 128, g1, be1, sc1, sh1);
  gemm_big<<<MBIG/128, 256, 0, stream>>>(H1, w2, b2, sc1, sh1, H2, Sp, Qp);
  stats_finish<<<128, 256, 0, stream>>>(Sp, Qp, NBLK_BIG, MBIG, 128, g2, be2, sc2, sh2);
  pool_kernel<<<128*MSMALL/256, 256, 0, stream>>>(H2, sc2, sh2, X3);

  gemm_k<64,0,1><<<MSMALL/64, 256, 0, stream>>>(X3, c1w, c1b, nullptr, nullptr, H3, Sp, Qp, MSMALL, 128, 0);
  stats_finish<<<128, 256, 0, stream>>>(Sp, Qp, NBLK_SMALL, MSMALL, 128, bg1, bb1, sc3, sh3);
  gemm_k<64,0,1><<<MSMALL/64, 256, 0, stream>>>(H3, Wp2, B2p, sc3, sh3, H4, Sp, Qp, MSMALL, 128, 1);
  stats_finish<<<128, 256, 0, stream>>>(Sp, Qp, NBLK_SMALL, MSMALL, 123, bg2, bb2, sc4, sh4);
  gemm_k<64,1,0><<<MSMALL/64, 256, 0, stream>>>(H4, Wp3, B3p, sc4, sh4, out, nullptr, nullptr, MSMALL, 128, 1);
}

// Round 17
// 827.869 us; speedup vs baseline: 1.0560x; 1.0560x over previous
//
#include <hip/hip_runtime.h>

#define N_PTS 16384
#define BATCH 16
#define NPROP 256
#define NSAMP 16
#define CFEAT 256
#define KIN 259      // 3 + C
#define KPAD 264
#define MBIG 65536   // B*P*NS
#define MSMALL 4096  // B*P
#define NOUT 119
#define NBLK_BIG 512
#define NBLK_SMALL 64

// ---------------- FPS (bit-exact vs numpy) + fused new_pos gather ----------------
// R13 proven best (448us). FPS campaign closed after 7 architectures.
#define FPS_LIST(M) M(0) M(1) M(2) M(3) M(4) M(5) M(6) M(7) \
  M(8) M(9) M(10) M(11) M(12) M(13) M(14) M(15) \
  M(16) M(17) M(18) M(19) M(20) M(21) M(22) M(23) \
  M(24) M(25) M(26) M(27) M(28) M(29) M(30) M(31)

#define FPS_PIN8(a,b,c,d,e,f,g,h) \
  asm volatile("" : "+v"(a), "+v"(b), "+v"(c), "+v"(d), \
                    "+v"(e), "+v"(f), "+v"(g), "+v"(h));

__global__ __attribute__((amdgpu_flat_work_group_size(512,512), amdgpu_waves_per_eu(2,2)))
void fps_kernel(const float* __restrict__ sp, const float* __restrict__ pos,
                int* __restrict__ idx_p, float* __restrict__ npos) {
#pragma clang fp contract(off)
  const int b = blockIdx.x;
  const int t = threadIdx.x;
  const int w = t >> 6;
  const int lane = t & 63;
  const float* base = sp + (size_t)b * N_PTS * 3;

#define FPS_DECL(J) float px##J, py##J, pz##J, dd##J;
  FPS_LIST(FPS_DECL)
#undef FPS_DECL

#define FPS_INIT(J) { const int i = t + J*512; \
    px##J = base[i*3+0]; py##J = base[i*3+1]; pz##J = base[i*3+2]; \
    dd##J = 1e10f; }
  FPS_LIST(FPS_INIT)
#undef FPS_INIT

  FPS_PIN8(px0,px1,px2,px3,px4,px5,px6,px7)
  FPS_PIN8(px8,px9,px10,px11,px12,px13,px14,px15)
  FPS_PIN8(px16,px17,px18,px19,px20,px21,px22,px23)
  FPS_PIN8(px24,px25,px26,px27,px28,px29,px30,px31)
  FPS_PIN8(py0,py1,py2,py3,py4,py5,py6,py7)
  FPS_PIN8(py8,py9,py10,py11,py12,py13,py14,py15)
  FPS_PIN8(py16,py17,py18,py19,py20,py21,py22,py23)
  FPS_PIN8(py24,py25,py26,py27,py28,py29,py30,py31)
  FPS_PIN8(pz0,pz1,pz2,pz3,pz4,pz5,pz6,pz7)
  FPS_PIN8(pz8,pz9,pz10,pz11,pz12,pz13,pz14,pz15)
  FPS_PIN8(pz16,pz17,pz18,pz19,pz20,pz21,pz22,pz23)
  FPS_PIN8(pz24,pz25,pz26,pz27,pz28,pz29,pz30,pz31)

  __shared__ unsigned long long part[2][8];
  __shared__ int sidx[NPROP];
  if (t == 0) { idx_p[b*NPROP] = 0; sidx[0] = 0; }
  float fx = base[0], fy = base[1], fz = base[2];
  for (int it = 1; it < NPROP; ++it) {
    float mv = -1.0f; int mi = 0;
#define FPS_STEP(J) { \
    float dx = px##J - fx, dy = py##J - fy, dz = pz##J - fz; \
    float d = (dx*dx + dy*dy) + dz*dz; \
    float nd = fminf(dd##J, d); \
    dd##J = nd; \
    if (nd > mv) { mv = nd; mi = t + J*512; } }
    FPS_LIST(FPS_STEP)
#undef FPS_STEP
    unsigned long long key =
      ((unsigned long long)__float_as_uint(mv) << 32) |
      (unsigned long long)(unsigned)(0x7FFFFFFF - mi);
#pragma unroll
    for (int o = 32; o > 0; o >>= 1) {
      unsigned long long ok = __shfl_xor(key, o, 64);
      if (ok > key) key = ok;
    }
    const int buf = it & 1;
    if (lane == 0) part[buf][w] = key;
    __syncthreads();
    unsigned long long k2 = part[buf][0];
#pragma unroll
    for (int q = 1; q < 8; ++q) {
      unsigned long long ok = part[buf][q];
      if (ok > k2) k2 = ok;
    }
    const int far = 0x7FFFFFFF - (int)(unsigned)(k2 & 0xFFFFFFFFull);
    if (t == 0) { idx_p[b*NPROP + it] = far; sidx[it] = far; }
    const float* fp = base + (size_t)far*3;
    fx = fp[0]; fy = fp[1]; fz = fp[2];
  }
  // fused new_pos gather (from pos, not seed_pos)
  __syncthreads();
  if (t < NPROP) {
    const int ii = sidx[t];
    const float* pp = pos + ((size_t)b*N_PTS + ii)*3;
    float* np = npos + (size_t)(b*NPROP + t)*3;
    np[0] = pp[0]; np[1] = pp[1]; np[2] = pp[2];
  }
}

// ---------------- ball query: 16 centers/block, LDS-staged chunks ----------------
// Block stages 1024-pt chunks (12KB, coalesced float4) into LDS; each of the
// 4 waves serves 4 centers from the staged chunk (1 ds_read_b128/test) with
// wave-uniform early-exit once cnt>=NSAMP. Chunks+groups ascend -> identical
// first-NS-in-index-order semantics (ballot-prefix slotting unchanged).
__global__ __launch_bounds__(256)
void ballq_kernel(const float* __restrict__ pos, const float* __restrict__ npos,
                  int* __restrict__ idxg) {
#pragma clang fp contract(off)
  __shared__ float4 pts[1024];     // 16 KB
  __shared__ int res[16][NSAMP];
  const int tid = threadIdx.x;
  const int w = tid >> 6, lane = tid & 63;
  const int c0 = blockIdx.x * 16;          // 256 blocks, 16 centers each
  const int b = c0 >> 8;                   // all 16 centers in same batch
  const float R2 = (float)(0.3*0.3);
  if (tid < 16) res[tid][0] = 0;
  float cx[4], cy[4], cz[4];
  int cnt[4];
#pragma unroll
  for (int j = 0; j < 4; ++j) {
    const int cid = c0 + w*4 + j;
    cx[j] = npos[cid*3+0]; cy[j] = npos[cid*3+1]; cz[j] = npos[cid*3+2];
    cnt[j] = 0;
  }
  const float4* pb4 = (const float4*)(pos + (size_t)b*N_PTS*3);
  const unsigned long long lmask = (1ull << lane) - 1ull;
  for (int ch = 0; ch < 16; ++ch) {
    // stage: thread loads 4 consecutive points (3 float4 = 12 floats)
    float4 A = pb4[ch*768 + tid*3 + 0];
    float4 B = pb4[ch*768 + tid*3 + 1];
    float4 C = pb4[ch*768 + tid*3 + 2];
    __syncthreads();                        // prior chunk fully consumed
    pts[tid*4+0] = make_float4(A.x, A.y, A.z, 0.f);
    pts[tid*4+1] = make_float4(A.w, B.x, B.y, 0.f);
    pts[tid*4+2] = make_float4(B.z, B.w, C.x, 0.f);
    pts[tid*4+3] = make_float4(C.y, C.z, C.w, 0.f);
    __syncthreads();
#pragma unroll
    for (int j = 0; j < 4; ++j) {
      if (cnt[j] < NSAMP) {                 // wave-uniform early exit
        int cj = cnt[j];
        for (int g = 0; g < 16; ++g) {
          const float4 v = pts[g*64 + lane];
          float dx = v.x - cx[j], dy = v.y - cy[j], dz = v.z - cz[j];
          float d2 = (dx*dx + dy*dy) + dz*dz;
          bool pred = d2 <= R2;
          unsigned long long bal = __ballot(pred);
          if (pred) {
            int slot = cj + (int)__popcll(bal & lmask);
            if (slot < NSAMP) res[w*4+j][slot] = ch*1024 + g*64 + lane;
          }
          cj += (int)__popcll(bal);
        }
        cnt[j] = cj;
      }
    }
  }
  __syncthreads();
  if (lane < NSAMP) {
#pragma unroll
    for (int j = 0; j < 4; ++j) {
      const int cid = c0 + w*4 + j;
      int v = res[w*4+j][lane];
      if (lane >= cnt[j]) v = res[w*4+j][0];
      idxg[cid*NSAMP + lane] = v;
    }
  }
}

// ---------------- weight padding ----------------
__global__ __launch_bounds__(256)
void prep_w(const float* __restrict__ w0, const float* __restrict__ c2w,
            const float* __restrict__ c2b, const float* __restrict__ c3w,
            const float* __restrict__ c3b,
            float* __restrict__ Wp0, float* __restrict__ Wp2, float* __restrict__ B2p,
            float* __restrict__ Wp3, float* __restrict__ B3p) {
  int g = blockIdx.x*256 + threadIdx.x;
  const int S0 = KPAD*128, S1 = S0 + 16384, S2 = S1 + 128, S3 = S2 + 16384, S4 = S3 + 128;
  if (g < S0) {
    int k = g >> 7, n = g & 127;
    Wp0[g] = (k < KIN) ? w0[k*128 + n] : 0.f;
  } else if (g < S1) {
    int g2 = g - S0; int k = g2 >> 7, n = g2 & 127;
    Wp2[g2] = (n < 123) ? c2w[k*123 + n] : 0.f;
  } else if (g < S2) {
    int n = g - S1;
    B2p[n] = (n < 123) ? c2b[n] : 0.f;
  } else if (g < S3) {
    int g2 = g - S2; int k = g2 >> 7, n = g2 & 127;
    Wp3[g2] = (k < 123 && n < NOUT) ? c3w[k*NOUT + n] : 0.f;
  } else if (g < S4) {
    int n = g - S3;
    B3p[n] = (n < NOUT) ? c3b[n] : 0.f;
  }
}

// ---------------- layer-0 GEMM with fused gather + fused partial stats ----------------
__global__ __launch_bounds__(256)
void gemm_l0(const float* __restrict__ pos, const float* __restrict__ npos,
             const float* __restrict__ feat, const int* __restrict__ idxg,
             const float* __restrict__ Wp, const float* __restrict__ bias,
             float* __restrict__ H, float* __restrict__ Sp, float* __restrict__ Qp) {
  __shared__ float As[8][128];
  __shared__ float Ws[8][128];
  __shared__ float pd[3][128];
  __shared__ int ids[128];
  const int tid = threadIdx.x;
  const int m0 = blockIdx.x * 128;
  const int b = m0 >> 12;
  const float* fb = feat + (size_t)b * CFEAT * N_PTS;
  if (tid < 128) {
    int m = m0 + tid;
    int ii = idxg[m];
    ids[tid] = ii;
    int q = m >> 4;
    const float* pp = pos + ((size_t)b*N_PTS + ii)*3;
    const float* cc = npos + (size_t)q*3;
    pd[0][tid] = pp[0] - cc[0];
    pd[1][tid] = pp[1] - cc[1];
    pd[2][tid] = pp[2] - cc[2];
  }
  __syncthreads();
  const int kr = tid >> 5;
  const int cm = (tid & 31) * 4;
  int ii_r[4];
#pragma unroll
  for (int x = 0; x < 4; ++x) ii_r[x] = ids[cm+x];
  float acc[8][8];
#pragma unroll
  for (int i = 0; i < 8; ++i)
#pragma unroll
    for (int j = 0; j < 8; ++j) acc[i][j] = 0.f;
  const int tm = tid & 15, tn = tid >> 4;
  for (int k0 = 0; k0 < KPAD; k0 += 8) {
    const int k = k0 + kr;
    float4 a0;
    if (k < 3) {
      a0.x = pd[k][cm+0]; a0.y = pd[k][cm+1]; a0.z = pd[k][cm+2]; a0.w = pd[k][cm+3];
    } else if (k < KIN) {
      const float* fr = fb + (size_t)(k-3)*N_PTS;
      a0.x = fr[ii_r[0]]; a0.y = fr[ii_r[1]]; a0.z = fr[ii_r[2]]; a0.w = fr[ii_r[3]];
    } else {
      a0 = make_float4(0.f,0.f,0.f,0.f);
    }
    float4 wv = *(const float4*)(Wp + (size_t)k*128 + cm);
    __syncthreads();
    *(float4*)&As[kr][cm] = a0;
    *(float4*)&Ws[kr][cm] = wv;
    __syncthreads();
#pragma unroll
    for (int kk = 0; kk < 8; ++kk) {
      float a[8], bb[8];
      *(float4*)(a)   = *(const float4*)&As[kk][tm*4];
      *(float4*)(a+4) = *(const float4*)&As[kk][tm*4 + 64];
      *(float4*)(bb)   = *(const float4*)&Ws[kk][tn*8];
      *(float4*)(bb+4) = *(const float4*)&Ws[kk][tn*8+4];
#pragma unroll
      for (int i = 0; i < 8; ++i)
#pragma unroll
        for (int j = 0; j < 8; ++j)
          acc[i][j] = fmaf(a[i], bb[j], acc[i][j]);
    }
  }
#pragma unroll
  for (int j = 0; j < 8; ++j) {
    const int n = tn*8 + j;
    const float bv = bias[n];
    float* cr = H + (size_t)n*MBIG + m0 + tm*4;
    float4 o0, o1;
    o0.x = acc[0][j]+bv; o0.y = acc[1][j]+bv; o0.z = acc[2][j]+bv; o0.w = acc[3][j]+bv;
    o1.x = acc[4][j]+bv; o1.y = acc[5][j]+bv; o1.z = acc[6][j]+bv; o1.w = acc[7][j]+bv;
    *(float4*)(cr)      = o0;
    *(float4*)(cr + 64) = o1;
    float s = o0.x+o0.y+o0.z+o0.w + o1.x+o1.y+o1.z+o1.w;
    float q = o0.x*o0.x+o0.y*o0.y+o0.z*o0.z+o0.w*o0.w
            + o1.x*o1.x+o1.y*o1.y+o1.z*o1.z+o1.w*o1.w;
#pragma unroll
    for (int o = 1; o < 16; o <<= 1) {
      s += __shfl_xor(s, o, 64);
      q += __shfl_xor(q, o, 64);
    }
    if (tm == 0) {
      Sp[(size_t)n*NBLK_BIG + blockIdx.x] = s;
      Qp[(size_t)n*NBLK_BIG + blockIdx.x] = q;
    }
  }
}

// ---------------- big GEMM (M=MBIG, K=N=128): W LDS-resident, dbuf A, 1 barrier/step ----------------
__global__ __launch_bounds__(256)
void gemm_big(const float* __restrict__ A, const float* __restrict__ W,
              const float* __restrict__ bias, const float* __restrict__ sc,
              const float* __restrict__ sh, float* __restrict__ C,
              float* __restrict__ Sp, float* __restrict__ Qp) {
  __shared__ float Ws[128][128];
  __shared__ float As[2][8][128];
  const int tid = threadIdx.x;
  const int m0 = blockIdx.x * 128;
  const int kr = tid >> 5;
  const int cw = (tid & 31) * 4;
  const int tm = tid & 15, tn = tid >> 4;
#pragma unroll
  for (int rr = 0; rr < 16; ++rr) {
    const int k = rr*8 + kr;
    *(float4*)&Ws[k][cw] = *(const float4*)(W + (size_t)k*128 + cw);
  }
  {
    float4 a0 = *(const float4*)(A + (size_t)kr*MBIG + m0 + cw);
    const float s_ = sc[kr], h_ = sh[kr];
    a0.x = fmaxf(fmaf(a0.x, s_, h_), 0.f);
    a0.y = fmaxf(fmaf(a0.y, s_, h_), 0.f);
    a0.z = fmaxf(fmaf(a0.z, s_, h_), 0.f);
    a0.w = fmaxf(fmaf(a0.w, s_, h_), 0.f);
    *(float4*)&As[0][kr][cw] = a0;
  }
  __syncthreads();
  float acc[8][8];
#pragma unroll
  for (int i = 0; i < 8; ++i)
#pragma unroll
    for (int j = 0; j < 8; ++j) acc[i][j] = 0.f;
  for (int step = 0; step < 16; ++step) {
    const int cur = step & 1;
    float4 a1;
    if (step < 15) {
      const int k = (step+1)*8 + kr;
      a1 = *(const float4*)(A + (size_t)k*MBIG + m0 + cw);
      const float s_ = sc[k], h_ = sh[k];
      a1.x = fmaxf(fmaf(a1.x, s_, h_), 0.f);
      a1.y = fmaxf(fmaf(a1.y, s_, h_), 0.f);
      a1.z = fmaxf(fmaf(a1.z, s_, h_), 0.f);
      a1.w = fmaxf(fmaf(a1.w, s_, h_), 0.f);
    }
#pragma unroll
    for (int kk = 0; kk < 8; ++kk) {
      float a[8], bb[8];
      *(float4*)(a)   = *(const float4*)&As[cur][kk][tm*4];
      *(float4*)(a+4) = *(const float4*)&As[cur][kk][tm*4 + 64];
      *(float4*)(bb)   = *(const float4*)&Ws[step*8+kk][tn*8];
      *(float4*)(bb+4) = *(const float4*)&Ws[step*8+kk][tn*8+4];
#pragma unroll
      for (int i = 0; i < 8; ++i)
#pragma unroll
        for (int j = 0; j < 8; ++j)
          acc[i][j] = fmaf(a[i], bb[j], acc[i][j]);
    }
    if (step < 15) *(float4*)&As[cur^1][kr][cw] = a1;
    __syncthreads();
  }
#pragma unroll
  for (int j = 0; j < 8; ++j) {
    const int n = tn*8 + j;
    const float bv = bias[n];
    float* cr = C + (size_t)n*MBIG + m0 + tm*4;
    float4 o0, o1;
    o0.x = acc[0][j]+bv; o0.y = acc[1][j]+bv; o0.z = acc[2][j]+bv; o0.w = acc[3][j]+bv;
    o1.x = acc[4][j]+bv; o1.y = acc[5][j]+bv; o1.z = acc[6][j]+bv; o1.w = acc[7][j]+bv;
    *(float4*)(cr)      = o0;
    *(float4*)(cr + 64) = o1;
    float s = o0.x+o0.y+o0.z+o0.w + o1.x+o1.y+o1.z+o1.w;
    float q = o0.x*o0.x+o0.y*o0.y+o0.z*o0.z+o0.w*o0.w
            + o1.x*o1.x+o1.y*o1.y+o1.z*o1.z+o1.w*o1.w;
#pragma unroll
    for (int o = 1; o < 16; o <<= 1) {
      s += __shfl_xor(s, o, 64);
      q += __shfl_xor(q, o, 64);
    }
    if (tm == 0) {
      Sp[(size_t)n*NBLK_BIG + blockIdx.x] = s;
      Qp[(size_t)n*NBLK_BIG + blockIdx.x] = q;
    }
  }
}

// ---------------- small GEMM, TM=64 tiles, optional fused partial stats ----------------
template<int TM, int MODE, int DOPART>
__global__ __launch_bounds__(256)
void gemm_k(const float* __restrict__ A, const float* __restrict__ W,
            const float* __restrict__ bias, const float* __restrict__ sc,
            const float* __restrict__ sh, float* __restrict__ C,
            float* __restrict__ Sp, float* __restrict__ Qp,
            int M, int K, int useT) {
  __shared__ float As[8][TM];
  __shared__ float Ws[8][128];
  const int tid = threadIdx.x;
  const int m0 = blockIdx.x * TM;
  const int kr = tid >> 5;
  const int cw = (tid & 31) * 4;
  const int tm = tid & 15, tn = tid >> 4;
  constexpr int MR = TM / 16;
  constexpr int NBLK = (TM == 128) ? NBLK_BIG : NBLK_SMALL;
  float acc[MR][8];
#pragma unroll
  for (int i = 0; i < MR; ++i)
#pragma unroll
    for (int j = 0; j < 8; ++j) acc[i][j] = 0.f;
  for (int k0 = 0; k0 < K; k0 += 8) {
    const float* ar = A + (size_t)(k0+kr)*M + m0;
    float4 wv = *(const float4*)(W + (size_t)(k0+kr)*128 + cw);
    const float s_ = useT ? sc[k0+kr] : 1.f;
    const float h_ = useT ? sh[k0+kr] : 0.f;
    const int c2 = (tid & 31) * 2;
    float2 a0 = *(const float2*)(ar + c2);
    if (useT) {
      a0.x = fmaxf(fmaf(a0.x, s_, h_), 0.f);
      a0.y = fmaxf(fmaf(a0.y, s_, h_), 0.f);
    }
    __syncthreads();
    *(float2*)&As[kr][c2] = a0;
    *(float4*)&Ws[kr][cw] = wv;
    __syncthreads();
#pragma unroll
    for (int kk = 0; kk < 8; ++kk) {
      float a[MR], bb[8];
      *(float4*)(a) = *(const float4*)&As[kk][tm*4];
      *(float4*)(bb)   = *(const float4*)&Ws[kk][tn*8];
      *(float4*)(bb+4) = *(const float4*)&Ws[kk][tn*8+4];
#pragma unroll
      for (int i = 0; i < MR; ++i)
#pragma unroll
        for (int j = 0; j < 8; ++j)
          acc[i][j] = fmaf(a[i], bb[j], acc[i][j]);
    }
  }
  if (MODE == 0) {
#pragma unroll
    for (int j = 0; j < 8; ++j) {
      const int n = tn*8 + j;
      const float bv = bias[n];
      float* cr = C + (size_t)n*M + m0 + tm*4;
      float4 o0;
      o0.x = acc[0][j]+bv; o0.y = acc[1][j]+bv; o0.z = acc[2][j]+bv; o0.w = acc[3][j]+bv;
      *(float4*)(cr) = o0;
      if constexpr (DOPART) {
        float s = o0.x+o0.y+o0.z+o0.w;
        float q = o0.x*o0.x+o0.y*o0.y+o0.z*o0.z+o0.w*o0.w;
#pragma unroll
        for (int o = 1; o < 16; o <<= 1) {
          s += __shfl_xor(s, o, 64);
          q += __shfl_xor(q, o, 64);
        }
        if (tm == 0) {
          Sp[(size_t)n*NBLK + blockIdx.x] = s;
          Qp[(size_t)n*NBLK + blockIdx.x] = q;
        }
      }
    }
  } else {
    const int bb_ = m0 >> 8;
    const int pcol = (m0 & 255) + tm*4;
#pragma unroll
    for (int j = 0; j < 8; ++j) {
      const int n = tn*8 + j;
      if (n < NOUT) {
        const float bv = bias[n];
        float* cr = C + ((size_t)bb_*NOUT + n)*256 + pcol;
        float4 o0;
        o0.x = acc[0][j]+bv; o0.y = acc[1][j]+bv; o0.z = acc[2][j]+bv; o0.w = acc[3][j]+bv;
        *(float4*)(cr) = o0;
      }
    }
  }
}

// ---------------- stats finish: reduce per-block partials -> (scale, shift) ----------------
__global__ __launch_bounds__(256)
void stats_finish(const float* __restrict__ Sp, const float* __restrict__ Qp,
                  int nblk, int M, int nc,
                  const float* __restrict__ g, const float* __restrict__ be,
                  float* __restrict__ sc, float* __restrict__ sh) {
  const int c = blockIdx.x;
  const int tid = threadIdx.x;
  if (c >= nc) { if (tid == 0) { sc[c] = 0.f; sh[c] = 0.f; } return; }
  float s = 0.f, q = 0.f;
  for (int i = tid; i < nblk; i += 256) {
    s += Sp[(size_t)c*nblk + i];
    q += Qp[(size_t)c*nblk + i];
  }
#pragma unroll
  for (int o = 32; o > 0; o >>= 1) {
    s += __shfl_xor(s, o, 64);
    q += __shfl_xor(q, o, 64);
  }
  __shared__ float ws_[4], wq_[4];
  const int w = tid >> 6, lane = tid & 63;
  if (lane == 0) { ws_[w] = s; wq_[w] = q; }
  __syncthreads();
  if (tid == 0) {
    float S = ws_[0]+ws_[1]+ws_[2]+ws_[3];
    float Q = wq_[0]+wq_[1]+wq_[2]+wq_[3];
    float mean = S / (float)M;
    float var  = Q / (float)M - mean*mean;
    float inv  = rsqrtf(var + 1e-5f);
    float gg = g[c];
    sc[c] = inv * gg;
    sh[c] = be[c] - mean * inv * gg;
  }
}

// ---------------- BN+ReLU then max over NSAMP ----------------
__global__ __launch_bounds__(256)
void pool_kernel(const float* __restrict__ H2, const float* __restrict__ sc,
                 const float* __restrict__ sh, float* __restrict__ X3) {
  int gidx = blockIdx.x*256 + threadIdx.x;
  int c = gidx >> 12;
  int q = gidx & 4095;
  const float* src = H2 + (size_t)c*MBIG + (size_t)q*NSAMP;
  float s_ = sc[c], h_ = sh[c];
  float m = 0.f;
#pragma unroll
  for (int k = 0; k < NSAMP; k += 4) {
    float4 v = *(const float4*)(src + k);
    m = fmaxf(m, fmaf(v.x, s_, h_));
    m = fmaxf(m, fmaf(v.y, s_, h_));
    m = fmaxf(m, fmaf(v.z, s_, h_));
    m = fmaxf(m, fmaf(v.w, s_, h_));
  }
  X3[(size_t)c*MSMALL + q] = m;
}

extern "C" void kernel_launch(void* const* d_in, const int* in_sizes, int n_in,
                              void* d_out, int out_size, void* d_ws, size_t ws_size,
                              hipStream_t stream) {
  const float* pos  = (const float*)d_in[0];
  const float* feat = (const float*)d_in[1];
  const float* spos = (const float*)d_in[2];
  const float* w0  = (const float*)d_in[3];
  const float* b0  = (const float*)d_in[4];
  const float* g0  = (const float*)d_in[5];
  const float* be0 = (const float*)d_in[6];
  const float* w1  = (const float*)d_in[7];
  const float* b1  = (const float*)d_in[8];
  const float* g1  = (const float*)d_in[9];
  const float* be1 = (const float*)d_in[10];
  const float* w2  = (const float*)d_in[11];
  const float* b2  = (const float*)d_in[12];
  const float* g2  = (const float*)d_in[13];
  const float* be2 = (const float*)d_in[14];
  const float* c1w = (const float*)d_in[15];
  const float* c1b = (const float*)d_in[16];
  const float* bg1 = (const float*)d_in[17];
  const float* bb1 = (const float*)d_in[18];
  const float* c2w = (const float*)d_in[19];
  const float* c2b = (const float*)d_in[20];
  const float* bg2 = (const float*)d_in[21];
  const float* bb2 = (const float*)d_in[22];
  const float* c3w = (const float*)d_in[23];
  const float* c3b = (const float*)d_in[24];
  float* out = (float*)d_out;

  float* fws = (float*)d_ws;
  size_t off = 0;
  auto alloc = [&](size_t n) { float* p = fws + off; off += n; return p; };
  float* H0  = alloc((size_t)128*MBIG);
  float* H1  = alloc((size_t)128*MBIG);
  float* X3  = alloc((size_t)128*MSMALL);
  float* H3  = alloc((size_t)128*MSMALL);
  float* H4  = alloc((size_t)128*MSMALL);
  float* Wp0 = alloc(KPAD*128);
  float* Wp2 = alloc(16384);
  float* B2p = alloc(128);
  float* Wp3 = alloc(16384);
  float* B3p = alloc(128);
  float* sc0 = alloc(128); float* sh0 = alloc(128);
  float* sc1 = alloc(128); float* sh1 = alloc(128);
  float* sc2 = alloc(128); float* sh2 = alloc(128);
  float* sc3 = alloc(128); float* sh3 = alloc(128);
  float* sc4 = alloc(128); float* sh4 = alloc(128);
  float* Sp  = alloc((size_t)128*NBLK_BIG);
  float* Qp  = alloc((size_t)128*NBLK_BIG);
  float* npos = alloc((size_t)BATCH*NPROP*3);
  int* idx_p = (int*)alloc(BATCH*NPROP);
  int* idxg  = (int*)alloc(MBIG);
  float* H2 = H0;

  fps_kernel<<<BATCH, 512, 0, stream>>>(spos, pos, idx_p, npos);
  ballq_kernel<<<BATCH*NPROP/16, 256, 0, stream>>>(pos, npos, idxg);
  prep_w<<<261, 256, 0, stream>>>(w0, c2w, c2b, c3w, c3b, Wp0, Wp2, B2p, Wp3, B3p);

  gemm_l0<<<MBIG/128, 256, 0, stream>>>(pos, npos, feat, idxg, Wp0, b0, H0, Sp, Qp);
  stats_finish<<<128, 256, 0, stream>>>(Sp, Qp, NBLK_BIG, MBIG, 128, g0, be0, sc0, sh0);
  gemm_big<<<MBIG/128, 256, 0, stream>>>(H0, w1, b1, sc0, sh0, H1, Sp, Qp);
  stats_finish<<<128, 256, 0, stream>>>(Sp, Qp, NBLK_BIG, MBIG, 128, g1, be1, sc1, sh1);
  gemm_big<<<MBIG/128, 256, 0, stream>>>(H1, w2, b2, sc1, sh1, H2, Sp, Qp);
  stats_finish<<<128, 256, 0, stream>>>(Sp, Qp, NBLK_BIG, MBIG, 128, g2, be2, sc2, sh2);
  pool_kernel<<<128*MSMALL/256, 256, 0, stream>>>(H2, sc2, sh2, X3);

  gemm_k<64,0,1><<<MSMALL/64, 256, 0, stream>>>(X3, c1w, c1b, nullptr, nullptr, H3, Sp, Qp, MSMALL, 128, 0);
  stats_finish<<<128, 256, 0, stream>>>(Sp, Qp, NBLK_SMALL, MSMALL, 128, bg1, bb1, sc3, sh3);
  gemm_k<64,0,1><<<MSMALL/64, 256, 0, stream>>>(H3, Wp2, B2p, sc3, sh3, H4, Sp, Qp, MSMALL, 128, 1);
  stats_finish<<<128, 256, 0, stream>>>(Sp, Qp, NBLK_SMALL, MSMALL, 123, bg2, bb2, sc4, sh4);
  gemm_k<64,1,0><<<MSMALL/64, 256, 0, stream>>>(H4, Wp3, B3p, sc4, sh4, out, nullptr, nullptr, MSMALL, 128, 1);
}